// Round 7
// baseline (821.820 us; speedup 1.0000x reference)
//
#include <hip/hip_runtime.h>

#define PI_F      3.14159265358979f
#define TWO_PI_F  6.28318530717959f
#define ALPHA_F   0.3f
#define NT        256
#define GBLK      1023   // 3 * 341; co-resident at 4 blocks/CU on 256 CUs
#define L1        13     // kz slots per pass-1 thread (2 threads cover a 25-line)
#define LPAD      26     // 2*L1 padded line length in psr/psi
#define RS2       32     // reduce parallel factor
#define M2        2      // atoms per pass-2 thread
#define LL        4      // k-lines per pass-2 block
#define ACHMAX    32     // max atoms per pass-1 slice (runtime ACH=18)

// sin/cos of 2*pi*u using the hardware trig units (input in revolutions).
__device__ __forceinline__ void sincos2pi(float u, float& s, float& c) {
#if __has_builtin(__builtin_amdgcn_fractf)
    float uf = __builtin_amdgcn_fractf(u);
#else
    float uf = u - floorf(u);
#endif
    asm("v_sin_f32 %0, %1" : "=v"(s) : "v"(uf));
    asm("v_cos_f32 %0, %1" : "=v"(c) : "v"(uf));
}

// 3x3 inverse (row-major).
__device__ __forceinline__ void inv3(const float* b, float* inv) {
    float c00 = b[4]*b[8] - b[5]*b[7];
    float c01 = b[2]*b[7] - b[1]*b[8];
    float c02 = b[1]*b[5] - b[2]*b[4];
    float c10 = b[5]*b[6] - b[3]*b[8];
    float c11 = b[0]*b[8] - b[2]*b[6];
    float c12 = b[2]*b[3] - b[0]*b[5];
    float c20 = b[3]*b[7] - b[4]*b[6];
    float c21 = b[1]*b[6] - b[0]*b[7];
    float c22 = b[0]*b[4] - b[1]*b[3];
    float det = b[0]*c00 + b[1]*c10 + b[2]*c20;
    float id = 1.0f/det;
    inv[0]=c00*id; inv[1]=c01*id; inv[2]=c02*id;
    inv[3]=c10*id; inv[4]=c11*id; inv[5]=c12*id;
    inv[6]=c20*id; inv[7]=c21*id; inv[8]=c22*id;
}

// original k index -> (line, slot); kz = slot - kmax.
__device__ __forceinline__ void kmap(int k, int kmax, int LINELEN, int& line, int& slot) {
    if (k < kmax) { line = 0; slot = k + 1 + kmax; }
    else { int r = k - kmax; line = 1 + r / LINELEN; slot = r % LINELEN; }
}

// grid-wide barrier: monotonic per-phase counter, device-scope atomics.
// Bounded spin converts a (theoretically impossible) residency deadlock into
// a validation failure instead of a hang.
__device__ __forceinline__ void gsync(int* cnt, int target) {
    __syncthreads();
    if (threadIdx.x == 0) {
        __threadfence();
        __hip_atomic_fetch_add(cnt, 1, __ATOMIC_RELEASE, __HIP_MEMORY_SCOPE_AGENT);
        int it = 0;
        while (__hip_atomic_load(cnt, __ATOMIC_ACQUIRE, __HIP_MEMORY_SCOPE_AGENT) < target
               && ++it < (1<<22)) {
            __builtin_amdgcn_s_sleep(2);
        }
        __threadfence();
    }
    __syncthreads();
}

__global__ __launch_bounds__(NT, 4) void k_fused(
        const float* __restrict__ coords, const float* __restrict__ box,
        const float* __restrict__ q, const float* __restrict__ p,
        const float* __restrict__ t, const float* __restrict__ kvecs,
        float* __restrict__ out, int* __restrict__ syncc,
        float* __restrict__ psr, float* __restrict__ psi,
        float* __restrict__ pred, float* __restrict__ pk2p,
        float* __restrict__ selfp, float* __restrict__ eblk,
        float* __restrict__ part,
        int N, int K, int kmax, int NL, int K2, int S1, int ACH, int AB, int LG) {
    const int bid = blockIdx.x, tid = threadIdx.x;
    const int LINELEN = 2*kmax + 1;
    float b[9], bi[9];
    #pragma unroll
    for (int j=0;j<9;++j) b[j]=box[j];
    inv3(b, bi);

    __shared__ float4 lat[(ACHMAX+1)*4];
    __shared__ float ebuf[4];

    // ================= P1: pass 1 (self-prepped LDS atoms) + self-energy =================
    {
        int slice = bid/3, sub = bid - slice*3;
        int n0 = slice*ACH;
        int mcnt = min(ACH, max(0, N - n0));
        float sq=0.f, sp=0.f, st=0.f;
        if (tid <= ACH) {
            int a = tid;
            float4 r0=make_float4(0.f,0.f,0.f,0.f), r1=r0, r2=r0, r3=r0;
            if (a < mcnt) {
                int n = n0 + a;
                const float c1 = TWO_PI_F*TWO_PI_F/3.0f;
                const float* tn = t + 9*(size_t)n;
                float rx=coords[3*n], ry=coords[3*n+1], rz=coords[3*n+2];
                float qq = q[n];
                float p0=p[3*n],p1=p[3*n+1],p2=p[3*n+2];
                float u1 = bi[0]*rx + bi[1]*ry + bi[2]*rz;
                float u2 = bi[3]*rx + bi[4]*ry + bi[5]*rz;
                float u3 = bi[6]*rx + bi[7]*ry + bi[8]*rz;
                float P1v = TWO_PI_F*(bi[0]*p0 + bi[1]*p1 + bi[2]*p2);
                float P2v = TWO_PI_F*(bi[3]*p0 + bi[4]*p1 + bi[5]*p2);
                float P3v = TWO_PI_F*(bi[6]*p0 + bi[7]*p1 + bi[8]*p2);
                float t0=tn[0],t1=tn[1],t2=tn[2],t3=tn[3],t4=tn[4],
                      t5=tn[5],t6=tn[6],t7=tn[7],t8=tn[8];
                float w1x = bi[0]*t0 + bi[1]*t3 + bi[2]*t6;
                float w1y = bi[0]*t1 + bi[1]*t4 + bi[2]*t7;
                float w1z = bi[0]*t2 + bi[1]*t5 + bi[2]*t8;
                float w2x = bi[3]*t0 + bi[4]*t3 + bi[5]*t6;
                float w2y = bi[3]*t1 + bi[4]*t4 + bi[5]*t7;
                float w2z = bi[3]*t2 + bi[4]*t5 + bi[5]*t8;
                float w3x = bi[6]*t0 + bi[7]*t3 + bi[8]*t6;
                float w3y = bi[6]*t1 + bi[7]*t4 + bi[8]*t7;
                float w3z = bi[6]*t2 + bi[7]*t5 + bi[8]*t8;
                float Q11 = w1x*bi[0] + w1y*bi[1] + w1z*bi[2];
                float Q12 = w1x*bi[3] + w1y*bi[4] + w1z*bi[5];
                float Q13 = w1x*bi[6] + w1y*bi[7] + w1z*bi[8];
                float Q21 = w2x*bi[0] + w2y*bi[1] + w2z*bi[2];
                float Q22 = w2x*bi[3] + w2y*bi[4] + w2z*bi[5];
                float Q23 = w2x*bi[6] + w2y*bi[7] + w2z*bi[8];
                float Q31 = w3x*bi[0] + w3y*bi[1] + w3z*bi[2];
                float Q32 = w3x*bi[3] + w3y*bi[4] + w3z*bi[5];
                float Q33 = w3x*bi[6] + w3y*bi[7] + w3z*bi[8];
                float c3v, s3v; sincos2pi(u3, s3v, c3v);
                r0 = make_float4(u1,u2,u3,qq);
                r1 = make_float4(c3v,s3v,P1v,P2v);
                r2 = make_float4(P3v,c1*Q11,c1*Q22,c1*Q33);
                r3 = make_float4(c1*(Q12+Q21),c1*(Q13+Q31),c1*(Q23+Q32),0.f);
                sq = qq*qq;
                sp = p0*p0 + p1*p1 + p2*p2;
                st = t0*t0+t1*t1+t2*t2+t3*t3+t4*t4+t5*t5+t6*t6+t7*t7+t8*t8;
            }
            lat[4*a+0]=r0; lat[4*a+1]=r1; lat[4*a+2]=r2; lat[4*a+3]=r3;
        }
        if (tid < 64) {
            for (int o=32;o;o>>=1){
                sq += __shfl_down(sq,o,64); sp += __shfl_down(sp,o,64); st += __shfl_down(st,o,64);
            }
            if (tid==0 && sub==0){
                selfp[4*slice+0]=sq; selfp[4*slice+1]=sp; selfp[4*slice+2]=st;
            }
        }
        __syncthreads();

        int seg = sub*NT + tid;
        bool act = seg < NL*2;
        int line = act ? (seg>>1) : 0;
        int half = seg & 1;
        int kxi=0, kyi=0;
        if (act) {
            if (line == 0) { kxi=0; kyi=0; }
            else if (line <= kmax) { kxi=0; kyi=line; }
            else { int lp = line - kmax - 1; kxi = 1 + lp/LINELEN; kyi = lp - (kxi-1)*LINELEN - kmax; }
        }
        float fkx = (float)kxi, fky = (float)kyi;
        float fkz0 = act ? (float)(half*L1 - kmax) : 0.f;
        float kx2 = fkx*fkx, kxky = fkx*fky, ky2 = fky*fky;
        float kz02 = fkz0*fkz0, tkz0 = 2.0f*fkz0;

        float sr[L1], si[L1];
        #pragma unroll
        for (int j=0;j<L1;++j){ sr[j]=0.f; si[j]=0.f; }

        float4 A0=lat[0],A1=lat[1],A2=lat[2],A3=lat[3];
        #pragma unroll 2
        for (int j=0;j<mcnt;++j) {
            float4 B0=lat[4*(j+1)+0], B1=lat[4*(j+1)+1];
            float4 B2=lat[4*(j+1)+2], B3=lat[4*(j+1)+3];
            float u1=A0.x, u2=A0.y, u3=A0.z, qn=A0.w;
            float c3=A1.x, s3=A1.y, P1v=A1.z, P2v=A1.w;
            float P3v=A2.x, M11=A2.y, M22=A2.z, M33=A2.w;
            float M12=A3.x, M13=A3.y, M23=A3.z;
            float ub = fkx*u1 + fky*u2 + fkz0*u3;
            float cc, ss; sincos2pi(ub, ss, cc);
            float Lib = fkx*P1v + fky*P2v + fkz0*P3v;
            float Aq = kx2*M11 + kxky*M12 + ky2*M22;
            float Bq = fkx*M13 + fky*M23;
            float Cq = M33;
            float A2q = Aq + fkz0*Bq + kz02*Cq;
            float B2q = fmaf(tkz0, Cq, Bq);
            #pragma unroll
            for (int jj=0;jj<L1;++jj) {
                float jf = (float)jj;
                float quad = fmaf(jf*jf, Cq, fmaf(jf, B2q, A2q));
                float Li = fmaf(jf, P3v, Lib);
                float Lr = qn - quad;
                sr[jj] = fmaf(cc, Lr, sr[jj]); sr[jj] = fmaf(-ss, Li, sr[jj]);
                si[jj] = fmaf(cc, Li, si[jj]); si[jj] = fmaf(ss, Lr, si[jj]);
                if (jj+1 < L1) {
                    float tmp = ss*s3;
                    float cn = fmaf(cc, c3, -tmp);
                    float tmp2 = cc*s3;
                    float sn = fmaf(ss, c3, tmp2);
                    cc = cn; ss = sn;
                }
            }
            A0=B0;A1=B1;A2=B2;A3=B3;
        }
        if (act) {
            size_t base = (size_t)slice*K2 + (size_t)line*LPAD + half*L1;
            #pragma unroll
            for (int j=0;j<L1;++j){ psr[base+j]=sr[j]; psi[base+j]=si[j]; }
        }
    }
    gsync(syncc+0, GBLK);

    // ================= P2a: partial reduce over slices (RS2-way) =================
    {
        int tg = bid*NT + tid;
        if (tg < RS2*K) {
            int rs = tg / K;
            int k  = tg - rs*K;
            int line, slot; kmap(k, kmax, LINELEN, line, slot);
            size_t pk = (size_t)line*LPAD + slot;
            float srr=0.f, sii=0.f;
            for (int s=rs; s<S1; s+=RS2){
                srr += psr[(size_t)s*K2 + pk];
                sii += psi[(size_t)s*K2 + pk];
            }
            pred[2*(size_t)tg+0]=srr; pred[2*(size_t)tg+1]=sii;
        }
    }
    gsync(syncc+1, GBLK);

    // ================= P2b: final reduce + gaussian + pk2p(+zeros) + energy partials ===
    {
        int tg = bid*NT + tid;
        float ek = 0.f;
        if (tg < NL*LINELEN) {
            int line = tg / LINELEN, slot = tg - line*LINELEN;
            int k = -1;
            if (line == 0) { if (slot >= kmax+1) k = slot - (kmax+1); }
            else k = kmax + (line-1)*LINELEN + slot;
            float srg=0.f, sig=0.f;
            if (k >= 0) {
                float srr=0.f, sii=0.f;
                #pragma unroll 8
                for (int rs=0; rs<RS2; ++rs){
                    srr += pred[((size_t)rs*K + k)*2 + 0];
                    sii += pred[((size_t)rs*K + k)*2 + 1];
                }
                float kx=kvecs[3*k], ky=kvecs[3*k+1], kz=kvecs[3*k+2];
                float ax = kx*bi[0] + ky*bi[3] + kz*bi[6];
                float ay = kx*bi[1] + ky*bi[4] + kz*bi[7];
                float az = kx*bi[2] + ky*bi[5] + kz*bi[8];
                float ksq = ax*ax + ay*ay + az*az;
                float g = expf(-PI_F*PI_F*ksq/(ALPHA_F*ALPHA_F)) / ksq;
                srg = g*srr; sig = g*sii;
                ek = srg*srr + sig*sii;
            }
            pk2p[2*(size_t)tg+0] = srg;
            pk2p[2*(size_t)tg+1] = sig;
        }
        int lane = tid & 63, w = tid >> 6;
        for (int o=32;o;o>>=1) ek += __shfl_down(ek,o,64);
        if (lane==0) ebuf[w]=ek;
        __syncthreads();
        if (tid==0) eblk[bid] = ebuf[0]+ebuf[1]+ebuf[2]+ebuf[3];
    }
    gsync(syncc+2, GBLK);

    // ================= P3: pass 2 (line walk, lattice-basis field) =================
    {
        if (bid < AB*LG) {
            int lg = bid / AB, ab = bid - lg*AB;
            int l0 = lg*LL, l1 = min(NL, l0+LL);
            float u1[M2],u2[M2],u3[M2],c3[M2],s3[M2];
            float pot[M2],F1[M2],F2[M2],F3[M2];
            #pragma unroll
            for (int m=0;m<M2;++m){
                int n = ab*(NT*M2) + m*NT + tid;
                float rx=0.f,ry=0.f,rz=0.f;
                if (n < N){ rx=coords[3*n]; ry=coords[3*n+1]; rz=coords[3*n+2]; }
                u1[m] = bi[0]*rx + bi[1]*ry + bi[2]*rz;
                u2[m] = bi[3]*rx + bi[4]*ry + bi[5]*rz;
                u3[m] = bi[6]*rx + bi[7]*ry + bi[8]*rz;
                sincos2pi(u3[m], s3[m], c3[m]);
                pot[m]=0.f; F1[m]=0.f; F2[m]=0.f; F3[m]=0.f;
            }
            float fkzb = -(float)kmax;
            for (int l = l0; l < l1; ++l) {
                int kxi, kyi;
                if (l == 0) { kxi=0; kyi=0; }
                else if (l <= kmax) { kxi=0; kyi=l; }
                else { int lp = l - kmax - 1; kxi = 1 + lp/LINELEN; kyi = lp - (kxi-1)*LINELEN - kmax; }
                float fkx = (float)kxi, fky = (float)kyi;
                const float* pl = pk2p + 2*(size_t)l*LINELEN;
                float cc[M2], ss[M2];
                #pragma unroll
                for (int m=0;m<M2;++m){
                    float ub = fkx*u1[m] + fky*u2[m] + fkzb*u3[m];
                    sincos2pi(ub, ss[m], cc[m]);
                }
                #pragma unroll 5
                for (int j=0;j<LINELEN;++j) {
                    float srg = pl[2*j], sig = pl[2*j+1];
                    float fkz = (float)(j - kmax);
                    #pragma unroll
                    for (int m=0;m<M2;++m){
                        pot[m] = fmaf(srg, cc[m], pot[m]);
                        pot[m] = fmaf(sig, ss[m], pot[m]);
                        float kim = srg*ss[m];
                        kim = fmaf(-sig, cc[m], kim);
                        F1[m] = fmaf(fkx, kim, F1[m]);
                        F2[m] = fmaf(fky, kim, F2[m]);
                        F3[m] = fmaf(fkz, kim, F3[m]);
                        float tmp = ss[m]*s3[m];
                        float cn = fmaf(cc[m], c3[m], -tmp);
                        float tmp2 = cc[m]*s3[m];
                        ss[m] = fmaf(ss[m], c3[m], tmp2);
                        cc[m] = cn;
                    }
                }
            }
            #pragma unroll
            for (int m=0;m<M2;++m) {
                int n = ab*(NT*M2) + m*NT + tid;
                if (n < N) {
                    float fx = F1[m]*bi[0] + F2[m]*bi[3] + F3[m]*bi[6];
                    float fy = F1[m]*bi[1] + F2[m]*bi[4] + F3[m]*bi[7];
                    float fz = F1[m]*bi[2] + F2[m]*bi[5] + F3[m]*bi[8];
                    part[(size_t)(0*LG+lg)*N+n]=pot[m];
                    part[(size_t)(1*LG+lg)*N+n]=fx;
                    part[(size_t)(2*LG+lg)*N+n]=fy;
                    part[(size_t)(3*LG+lg)*N+n]=fz;
                }
            }
        }
    }
    gsync(syncc+3, GBLK);

    // ================= P4: finalize outputs + energy =================
    {
        float V = b[0]*(b[4]*b[8]-b[5]*b[7]) + b[1]*(b[5]*b[6]-b[3]*b[8])
                + b[2]*(b[3]*b[7]-b[4]*b[6]);
        float arpi = ALPHA_F/sqrtf(PI_F);
        float a2 = ALPHA_F*ALPHA_F;
        int tg = bid*NT + tid;
        if (tg < 4*N) {
            int c = tg / N;
            int n = tg - c*N;
            float sum = 0.f;
            #pragma unroll 4
            for (int s=0;s<LG;++s) sum += part[(size_t)(c*LG+s)*N+n];
            if (c == 0) {
                out[1+n] = (2.0f/(PI_F*V))*sum - 2.0f*arpi*q[n];
            } else {
                float cp2 = arpi*(4.0f*a2/3.0f);
                out[1+N+3*n+(c-1)] = (4.0f/V)*sum + cp2*p[3*n+(c-1)];
            }
        }
        int base = ((4*N + 63)/64)*64;
        if (tg >= base && tg < base + 64) {
            int lane = tg - base;
            float e=0.f, sq=0.f, sp=0.f, st=0.f;
            for (int i=lane;i<GBLK;i+=64) e += eblk[i];
            for (int i=lane;i<S1;i+=64){ sq+=selfp[4*i]; sp+=selfp[4*i+1]; st+=selfp[4*i+2]; }
            for (int o=32;o;o>>=1) {
                e += __shfl_down(e,o,64); sq += __shfl_down(sq,o,64);
                sp += __shfl_down(sp,o,64); st += __shfl_down(st,o,64);
            }
            if (lane==0) {
                out[0] = e/(PI_F*V) - arpi*sq - arpi*(2.0f*a2/3.0f)*sp
                       - arpi*(8.0f*a2*a2/45.0f)*st;
            }
        }
    }
}

extern "C" void kernel_launch(void* const* d_in, const int* in_sizes, int n_in,
                              void* d_out, int out_size, void* d_ws, size_t ws_size,
                              hipStream_t stream) {
    const float* coords = (const float*)d_in[0];
    const float* box    = (const float*)d_in[1];
    const float* q      = (const float*)d_in[2];
    const float* p      = (const float*)d_in[3];
    const float* t      = (const float*)d_in[4];
    const float* kvecs  = (const float*)d_in[5];
    int N = in_sizes[0]/3;
    int K = in_sizes[5]/3;

    int kmax = 12;
    for (int km=1; km<=40; ++km) {
        long ll = 2l*km+1;
        if ((long)km*(ll*ll + ll + 1) == (long)K) { kmax = km; break; }
    }
    int LINELEN = 2*kmax+1;                 // 25
    int NL = 1 + kmax + kmax*LINELEN;       // 313
    int K2 = NL*LPAD;                       // 8138
    int S1 = GBLK/3;                        // 341
    int ACH = (N + S1 - 1)/S1;              // 18
    int AB = (N + NT*M2 - 1)/(NT*M2);       // 12
    int LG = (NL + LL - 1)/LL;              // 79

    float* ws = (float*)d_ws;
    int* syncc = (int*)d_ws;                // 16 ints, zeroed below
    size_t off = 16;
    float* psr   = ws + off; off += (size_t)S1*K2;
    float* psi   = ws + off; off += (size_t)S1*K2;
    float* pred  = ws + off; off += 2*(size_t)RS2*K;
    float* pk2p  = ws + off; off += 2*(size_t)NL*LINELEN;
    float* selfp = ws + off; off += 4*(size_t)S1;
    float* eblk  = ws + off; off += (size_t)GBLK + 64;
    float* part  = ws + off; off += 4*(size_t)LG*N;

    hipMemsetAsync(d_ws, 0, 64, stream);    // zero the barrier counters (captured)

    k_fused<<<GBLK, NT, 0, stream>>>(coords, box, q, p, t, kvecs,
                                     (float*)d_out, syncc,
                                     psr, psi, pred, pk2p, selfp, eblk, part,
                                     N, K, kmax, NL, K2, S1, ACH, AB, LG);
}

// Round 8
// 72.429 us; speedup vs baseline: 11.3466x; 11.3466x over previous
//
#include <hip/hip_runtime.h>

#define PI_F      3.14159265358979f
#define TWO_PI_F  6.28318530717959f
#define ALPHA_F   0.3f
#define NT        256
#define NT1       128   // pass-1 block size
#define NT2       128   // pass-2 block size
#define L1        13    // kz slots per pass-1 thread (2 threads cover a 25-line)
#define LPAD      26    // padded line length in psr/psi
#define RS2       16    // reduce parallel factor
#define M2        4     // atoms per pass-2 thread
#define LL        2     // k-lines per pass-2 block
#define ACHMAX    32    // max atoms per pass-1 slice (runtime ~30)

// sin/cos of 2*pi*u using the hardware trig units (input in revolutions).
__device__ __forceinline__ void sincos2pi(float u, float& s, float& c) {
#if __has_builtin(__builtin_amdgcn_fractf)
    float uf = __builtin_amdgcn_fractf(u);
#else
    float uf = u - floorf(u);
#endif
    asm("v_sin_f32 %0, %1" : "=v"(s) : "v"(uf));
    asm("v_cos_f32 %0, %1" : "=v"(c) : "v"(uf));
}

// 3x3 inverse (row-major).
__device__ __forceinline__ void inv3(const float* b, float* inv) {
    float c00 = b[4]*b[8] - b[5]*b[7];
    float c01 = b[2]*b[7] - b[1]*b[8];
    float c02 = b[1]*b[5] - b[2]*b[4];
    float c10 = b[5]*b[6] - b[3]*b[8];
    float c11 = b[0]*b[8] - b[2]*b[6];
    float c12 = b[2]*b[3] - b[0]*b[5];
    float c20 = b[3]*b[7] - b[4]*b[6];
    float c21 = b[1]*b[6] - b[0]*b[7];
    float c22 = b[0]*b[4] - b[1]*b[3];
    float det = b[0]*c00 + b[1]*c10 + b[2]*c20;
    float id = 1.0f/det;
    inv[0]=c00*id; inv[1]=c01*id; inv[2]=c02*id;
    inv[3]=c10*id; inv[4]=c11*id; inv[5]=c12*id;
    inv[6]=c20*id; inv[7]=c21*id; inv[8]=c22*id;
}

// original k index -> (line, slot); kz = slot - kmax.
__device__ __forceinline__ void kmap(int k, int kmax, int LINELEN, int& line, int& slot) {
    if (k < kmax) { line = 0; slot = k + 1 + kmax; }
    else { int r = k - kmax; line = 1 + r / LINELEN; slot = r % LINELEN; }
}

// line index -> (kx,ky)
__device__ __forceinline__ void lmap(int line, int kmax, int LINELEN, int& kxi, int& kyi) {
    if (line == 0) { kxi=0; kyi=0; }
    else if (line <= kmax) { kxi=0; kyi=line; }
    else { int lp = line - kmax - 1; kxi = 1 + lp/LINELEN; kyi = lp - (kxi-1)*LINELEN - kmax; }
}

// ---------------- pass 1 (fused atom-prep + self-energy partials) ----------------
// grid (gx1, S1): y-block = one slice of ACH atoms (self-prepped into LDS);
// thread owns half a (kx,ky) line (L1 kz slots), phase recurrence along kz.
__global__ __launch_bounds__(NT1) void k_pass1(
        const float* __restrict__ coords, const float* __restrict__ box,
        const float* __restrict__ q, const float* __restrict__ p,
        const float* __restrict__ t,
        float* __restrict__ psr, float* __restrict__ psi, float* __restrict__ selfp,
        int N, int kmax, int NL, int K2, int ACH) {
    const int tid = threadIdx.x;
    const int LINELEN = 2*kmax + 1;
    float b[9], bi[9];
    #pragma unroll
    for (int j=0;j<9;++j) b[j]=box[j];
    inv3(b, bi);

    __shared__ float4 lat[(ACHMAX+1)*4];
    int slice = blockIdx.y;
    int n0 = slice*ACH;
    int mcnt = min(ACH, max(0, N - n0));
    float sq=0.f, sp=0.f, st=0.f;
    if (tid <= ACH) {
        int a = tid;
        float4 r0=make_float4(0.f,0.f,0.f,0.f), r1=r0, r2=r0, r3=r0;
        if (a < mcnt) {
            int n = n0 + a;
            const float c1 = TWO_PI_F*TWO_PI_F/3.0f;
            const float* tn = t + 9*(size_t)n;
            float rx=coords[3*n], ry=coords[3*n+1], rz=coords[3*n+2];
            float qq = q[n];
            float p0=p[3*n],p1=p[3*n+1],p2=p[3*n+2];
            float u1 = bi[0]*rx + bi[1]*ry + bi[2]*rz;
            float u2 = bi[3]*rx + bi[4]*ry + bi[5]*rz;
            float u3 = bi[6]*rx + bi[7]*ry + bi[8]*rz;
            float P1v = TWO_PI_F*(bi[0]*p0 + bi[1]*p1 + bi[2]*p2);
            float P2v = TWO_PI_F*(bi[3]*p0 + bi[4]*p1 + bi[5]*p2);
            float P3v = TWO_PI_F*(bi[6]*p0 + bi[7]*p1 + bi[8]*p2);
            float t0=tn[0],t1=tn[1],t2=tn[2],t3=tn[3],t4=tn[4],
                  t5=tn[5],t6=tn[6],t7=tn[7],t8=tn[8];
            float w1x = bi[0]*t0 + bi[1]*t3 + bi[2]*t6;
            float w1y = bi[0]*t1 + bi[1]*t4 + bi[2]*t7;
            float w1z = bi[0]*t2 + bi[1]*t5 + bi[2]*t8;
            float w2x = bi[3]*t0 + bi[4]*t3 + bi[5]*t6;
            float w2y = bi[3]*t1 + bi[4]*t4 + bi[5]*t7;
            float w2z = bi[3]*t2 + bi[4]*t5 + bi[5]*t8;
            float w3x = bi[6]*t0 + bi[7]*t3 + bi[8]*t6;
            float w3y = bi[6]*t1 + bi[7]*t4 + bi[8]*t7;
            float w3z = bi[6]*t2 + bi[7]*t5 + bi[8]*t8;
            float Q11 = w1x*bi[0] + w1y*bi[1] + w1z*bi[2];
            float Q12 = w1x*bi[3] + w1y*bi[4] + w1z*bi[5];
            float Q13 = w1x*bi[6] + w1y*bi[7] + w1z*bi[8];
            float Q21 = w2x*bi[0] + w2y*bi[1] + w2z*bi[2];
            float Q22 = w2x*bi[3] + w2y*bi[4] + w2z*bi[5];
            float Q23 = w2x*bi[6] + w2y*bi[7] + w2z*bi[8];
            float Q31 = w3x*bi[0] + w3y*bi[1] + w3z*bi[2];
            float Q32 = w3x*bi[3] + w3y*bi[4] + w3z*bi[5];
            float Q33 = w3x*bi[6] + w3y*bi[7] + w3z*bi[8];
            float c3v, s3v; sincos2pi(u3, s3v, c3v);
            r0 = make_float4(u1,u2,u3,qq);
            r1 = make_float4(c3v,s3v,P1v,P2v);
            r2 = make_float4(P3v,c1*Q11,c1*Q22,c1*Q33);
            r3 = make_float4(c1*(Q12+Q21),c1*(Q13+Q31),c1*(Q23+Q32),0.f);
            sq = qq*qq;
            sp = p0*p0 + p1*p1 + p2*p2;
            st = t0*t0+t1*t1+t2*t2+t3*t3+t4*t4+t5*t5+t6*t6+t7*t7+t8*t8;
        }
        lat[4*a+0]=r0; lat[4*a+1]=r1; lat[4*a+2]=r2; lat[4*a+3]=r3;
    }
    if (blockIdx.x == 0 && tid < 64) {
        for (int o=32;o;o>>=1){
            sq += __shfl_down(sq,o,64); sp += __shfl_down(sp,o,64); st += __shfl_down(st,o,64);
        }
        if (tid==0){
            selfp[4*slice+0]=sq; selfp[4*slice+1]=sp; selfp[4*slice+2]=st;
        }
    }
    __syncthreads();

    int seg = blockIdx.x*NT1 + tid;
    bool act = seg < NL*2;
    int line = act ? (seg>>1) : 0;
    int half = seg & 1;
    int kxi=0, kyi=0;
    if (act) lmap(line, kmax, LINELEN, kxi, kyi);
    float fkx = (float)kxi, fky = (float)kyi;
    float fkz0 = act ? (float)(half*L1 - kmax) : 0.f;
    float kx2 = fkx*fkx, kxky = fkx*fky, ky2 = fky*fky;
    float kz02 = fkz0*fkz0, tkz0 = 2.0f*fkz0;

    float sr[L1], si[L1];
    #pragma unroll
    for (int j=0;j<L1;++j){ sr[j]=0.f; si[j]=0.f; }

    float4 A0=lat[0],A1=lat[1],A2=lat[2],A3=lat[3];
    #pragma unroll 2
    for (int j=0;j<mcnt;++j) {
        float4 B0=lat[4*(j+1)+0], B1=lat[4*(j+1)+1];
        float4 B2=lat[4*(j+1)+2], B3=lat[4*(j+1)+3];
        float u1=A0.x, u2=A0.y, u3=A0.z, qn=A0.w;
        float c3=A1.x, s3=A1.y, P1v=A1.z, P2v=A1.w;
        float P3v=A2.x, M11=A2.y, M22=A2.z, M33=A2.w;
        float M12=A3.x, M13=A3.y, M23=A3.z;
        float ub = fkx*u1 + fky*u2 + fkz0*u3;
        float cc, ss; sincos2pi(ub, ss, cc);
        float Lib = fkx*P1v + fky*P2v + fkz0*P3v;
        float Aq = kx2*M11 + kxky*M12 + ky2*M22;
        float Bq = fkx*M13 + fky*M23;
        float Cq = M33;
        float A2q = Aq + fkz0*Bq + kz02*Cq;
        float B2q = fmaf(tkz0, Cq, Bq);
        #pragma unroll
        for (int jj=0;jj<L1;++jj) {
            float jf = (float)jj;
            float quad = fmaf(jf*jf, Cq, fmaf(jf, B2q, A2q));
            float Li = fmaf(jf, P3v, Lib);
            float Lr = qn - quad;
            sr[jj] = fmaf(cc, Lr, sr[jj]); sr[jj] = fmaf(-ss, Li, sr[jj]);
            si[jj] = fmaf(cc, Li, si[jj]); si[jj] = fmaf(ss, Lr, si[jj]);
            if (jj+1 < L1) {
                float tmp = ss*s3;
                float cn = fmaf(cc, c3, -tmp);
                float tmp2 = cc*s3;
                float sn = fmaf(ss, c3, tmp2);
                cc = cn; ss = sn;
            }
        }
        A0=B0;A1=B1;A2=B2;A3=B3;
    }
    if (act) {
        size_t base = (size_t)slice*K2 + (size_t)line*LPAD + half*L1;
        #pragma unroll
        for (int j=0;j<L1;++j){ psr[base+j]=sr[j]; psi[base+j]=si[j]; }
    }
}

// ---------------- reduce1: RS2-way partial reduce over slices ----------------
__global__ __launch_bounds__(NT) void k_reduce1(const float* __restrict__ psr,
        const float* __restrict__ psi, float* __restrict__ pred,
        int K, int K2, int S1, int kmax) {
    int tg = blockIdx.x*NT + threadIdx.x;
    if (tg >= RS2*K) return;
    int LINELEN = 2*kmax+1;
    int rs = tg / K;
    int k  = tg - rs*K;
    int line, slot; kmap(k, kmax, LINELEN, line, slot);
    size_t pk = (size_t)line*LPAD + slot;
    float srr=0.f, sii=0.f;
    #pragma unroll 4
    for (int s=rs; s<S1; s+=RS2){
        srr += psr[(size_t)s*K2 + pk];
        sii += psi[(size_t)s*K2 + pk];
    }
    pred[2*(size_t)tg+0]=srr; pred[2*(size_t)tg+1]=sii;
}

// ---------------- reduce2: final reduce + gaussian + pk2p + energy partials ----------------
__global__ __launch_bounds__(NT) void k_reduce2(const float* __restrict__ pred,
        const float* __restrict__ kvecs, const float* __restrict__ box,
        float* __restrict__ pk2p, float* __restrict__ eblk, int K, int kmax, int NL) {
    float b[9], bi[9];
    #pragma unroll
    for (int j=0;j<9;++j) b[j]=box[j];
    inv3(b, bi);
    int LINELEN = 2*kmax+1;
    int tg = blockIdx.x*NT + threadIdx.x;
    float ek = 0.f;
    if (tg < NL*LINELEN) {
        int line = tg / LINELEN, slot = tg - line*LINELEN;
        int k = -1;
        if (line == 0) { if (slot >= kmax+1) k = slot - (kmax+1); }
        else k = kmax + (line-1)*LINELEN + slot;
        float srg=0.f, sig=0.f;
        if (k >= 0) {
            float srr=0.f, sii=0.f;
            #pragma unroll 8
            for (int rs=0; rs<RS2; ++rs){
                srr += pred[((size_t)rs*K + k)*2 + 0];
                sii += pred[((size_t)rs*K + k)*2 + 1];
            }
            float kx=kvecs[3*k], ky=kvecs[3*k+1], kz=kvecs[3*k+2];
            float ax = kx*bi[0] + ky*bi[3] + kz*bi[6];
            float ay = kx*bi[1] + ky*bi[4] + kz*bi[7];
            float az = kx*bi[2] + ky*bi[5] + kz*bi[8];
            float ksq = ax*ax + ay*ay + az*az;
            float g = expf(-PI_F*PI_F*ksq/(ALPHA_F*ALPHA_F)) / ksq;
            srg = g*srr; sig = g*sii;
            ek = srg*srr + sig*sii;
        }
        pk2p[2*(size_t)tg+0] = srg;
        pk2p[2*(size_t)tg+1] = sig;
    }
    __shared__ float ebuf[4];
    int lane = threadIdx.x & 63, w = threadIdx.x >> 6;
    for (int o=32;o;o>>=1) ek += __shfl_down(ek,o,64);
    if (lane==0) ebuf[w]=ek;
    __syncthreads();
    if (threadIdx.x==0) eblk[blockIdx.x] = ebuf[0]+ebuf[1]+ebuf[2]+ebuf[3];
}

// ---------------- pass 2: thread owns M2 atoms, walks k-lines with phase recurrence ----------------
__global__ __launch_bounds__(NT2) void k_pass2(const float* __restrict__ coords,
        const float* __restrict__ box, const float* __restrict__ pk2p,
        float* __restrict__ part, int N, int NL, int kmax) {
    float b[9], bi[9];
    #pragma unroll
    for (int j=0;j<9;++j) b[j]=box[j];
    inv3(b, bi);
    int LINELEN = 2*kmax+1;
    int S2 = gridDim.y, s0 = blockIdx.y;
    int NSTEP = gridDim.x*NT2;
    int nbase = blockIdx.x*NT2 + threadIdx.x;
    float u1[M2],u2[M2],u3[M2],c3[M2],s3[M2];
    float pot[M2],F1[M2],F2[M2],F3[M2];
    #pragma unroll
    for (int m=0;m<M2;++m){
        int n = nbase + m*NSTEP;
        float rx=0.f,ry=0.f,rz=0.f;
        if (n < N){ rx=coords[3*n]; ry=coords[3*n+1]; rz=coords[3*n+2]; }
        u1[m] = bi[0]*rx + bi[1]*ry + bi[2]*rz;
        u2[m] = bi[3]*rx + bi[4]*ry + bi[5]*rz;
        u3[m] = bi[6]*rx + bi[7]*ry + bi[8]*rz;
        sincos2pi(u3[m], s3[m], c3[m]);
        pot[m]=0.f; F1[m]=0.f; F2[m]=0.f; F3[m]=0.f;
    }
    float fkzb = -(float)kmax;
    for (int lg = s0; lg*LL < NL; lg += S2) {
        int l0 = lg*LL, l1 = min(NL, l0+LL);
        for (int l = l0; l < l1; ++l) {
            int kxi, kyi; lmap(l, kmax, LINELEN, kxi, kyi);
            float fkx = (float)kxi, fky = (float)kyi;
            const float* pl = pk2p + 2*(size_t)l*LINELEN;
            float cc[M2], ss[M2];
            #pragma unroll
            for (int m=0;m<M2;++m){
                float ub = fkx*u1[m] + fky*u2[m] + fkzb*u3[m];
                sincos2pi(ub, ss[m], cc[m]);
            }
            #pragma unroll 5
            for (int j=0;j<LINELEN;++j) {
                float srg = pl[2*j], sig = pl[2*j+1];
                float fkz = (float)(j - kmax);
                #pragma unroll
                for (int m=0;m<M2;++m){
                    pot[m] = fmaf(srg, cc[m], pot[m]);
                    pot[m] = fmaf(sig, ss[m], pot[m]);
                    float kim = srg*ss[m];
                    kim = fmaf(-sig, cc[m], kim);
                    F1[m] = fmaf(fkx, kim, F1[m]);
                    F2[m] = fmaf(fky, kim, F2[m]);
                    F3[m] = fmaf(fkz, kim, F3[m]);
                    float tmp = ss[m]*s3[m];
                    float cn = fmaf(cc[m], c3[m], -tmp);
                    float tmp2 = cc[m]*s3[m];
                    ss[m] = fmaf(ss[m], c3[m], tmp2);
                    cc[m] = cn;
                }
            }
        }
    }
    #pragma unroll
    for (int m=0;m<M2;++m) {
        int n = nbase + m*NSTEP;
        if (n < N) {
            float fx = F1[m]*bi[0] + F2[m]*bi[3] + F3[m]*bi[6];
            float fy = F1[m]*bi[1] + F2[m]*bi[4] + F3[m]*bi[7];
            float fz = F1[m]*bi[2] + F2[m]*bi[5] + F3[m]*bi[8];
            part[(size_t)(0*S2+s0)*N+n]=pot[m];
            part[(size_t)(1*S2+s0)*N+n]=fx;
            part[(size_t)(2*S2+s0)*N+n]=fy;
            part[(size_t)(3*S2+s0)*N+n]=fz;
        }
    }
}

// ---------------- finalize: block 0 = energy; rest = one thread per output scalar ----------------
__global__ __launch_bounds__(NT) void k_fin(const float* __restrict__ part,
                      const float* __restrict__ q,
                      const float* __restrict__ p, const float* __restrict__ box,
                      const float* __restrict__ eblk, int nblk,
                      const float* __restrict__ selfp, int nself,
                      float* __restrict__ out, int N, int S2) {
    float b[9];
    #pragma unroll
    for (int j=0;j<9;++j) b[j]=box[j];
    float V = b[0]*(b[4]*b[8]-b[5]*b[7]) + b[1]*(b[5]*b[6]-b[3]*b[8]) + b[2]*(b[3]*b[7]-b[4]*b[6]);
    float arpi = ALPHA_F/sqrtf(PI_F);
    float a2 = ALPHA_F*ALPHA_F;
    if (blockIdx.x == 0) {
        int lane = threadIdx.x;
        if (lane >= 64) return;
        float e=0.f, sq=0.f, sp=0.f, st=0.f;
        for (int i=lane;i<nblk;i+=64) e += eblk[i];
        for (int i=lane;i<nself;i+=64){ sq+=selfp[4*i]; sp+=selfp[4*i+1]; st+=selfp[4*i+2]; }
        for (int o=32;o;o>>=1) {
            e += __shfl_down(e,o,64); sq += __shfl_down(sq,o,64);
            sp += __shfl_down(sp,o,64); st += __shfl_down(st,o,64);
        }
        if (lane==0) {
            out[0] = e/(PI_F*V) - arpi*sq - arpi*(2.0f*a2/3.0f)*sp
                   - arpi*(8.0f*a2*a2/45.0f)*st;
        }
        return;
    }
    int tg = (blockIdx.x-1)*NT + threadIdx.x;
    if (tg >= 4*N) return;
    int c = tg / N;
    int n = tg - c*N;
    float sum = 0.f;
    #pragma unroll 4
    for (int s=0;s<S2;++s) sum += part[(size_t)(c*S2+s)*N+n];
    if (c == 0) {
        out[1+n] = (2.0f/(PI_F*V))*sum - 2.0f*arpi*q[n];
    } else {
        float cp2 = arpi*(4.0f*a2/3.0f);
        out[1+N+3*n+(c-1)] = (4.0f/V)*sum + cp2*p[3*n+(c-1)];
    }
}

extern "C" void kernel_launch(void* const* d_in, const int* in_sizes, int n_in,
                              void* d_out, int out_size, void* d_ws, size_t ws_size,
                              hipStream_t stream) {
    const float* coords = (const float*)d_in[0];
    const float* box    = (const float*)d_in[1];
    const float* q      = (const float*)d_in[2];
    const float* p      = (const float*)d_in[3];
    const float* t      = (const float*)d_in[4];
    const float* kvecs  = (const float*)d_in[5];
    int N = in_sizes[0]/3;
    int K = in_sizes[5]/3;

    int kmax = 12;
    for (int km=1; km<=40; ++km) {
        long ll = 2l*km+1;
        if ((long)km*(ll*ll + ll + 1) == (long)K) { kmax = km; break; }
    }
    int LINELEN = 2*kmax+1;                 // 25
    int NL = 1 + kmax + kmax*LINELEN;       // 313
    int K2 = NL*LPAD;                       // 8138
    int S1 = (N + 29)/30;                   // 200 slices
    int ACH = (N + S1 - 1)/S1;              // 30 atoms/slice (<= ACHMAX)
    int S2 = (NL + LL - 1)/LL;              // 157
    int gx1 = (2*NL + NT1 - 1)/NT1;         // 5
    int gx2 = ((N + M2 - 1)/M2 + NT2 - 1)/NT2;  // 12

    float* ws = (float*)d_ws;
    size_t off = 0;
    float* psr   = ws + off; off += (size_t)S1*K2;
    float* psi   = ws + off; off += (size_t)S1*K2;
    float* pred  = ws + off; off += 2*(size_t)RS2*K;
    float* pk2p  = ws + off; off += 2*(size_t)NL*LINELEN;
    float* selfp = ws + off; off += 4*(size_t)S1;
    float* eblk  = ws + off; off += 256;
    float* part  = ws + off; off += 4*(size_t)S2*N;

    dim3 g1(gx1, S1);
    k_pass1<<<g1, NT1, 0, stream>>>(coords, box, q, p, t, psr, psi, selfp,
                                    N, kmax, NL, K2, ACH);

    int rb = (RS2*K + NT - 1)/NT;
    k_reduce1<<<rb, NT, 0, stream>>>(psr, psi, pred, K, K2, S1, kmax);

    int r2b = (NL*LINELEN + NT - 1)/NT;     // 31
    k_reduce2<<<r2b, NT, 0, stream>>>(pred, kvecs, box, pk2p, eblk, K, kmax, NL);

    dim3 g2(gx2, S2);
    k_pass2<<<g2, NT2, 0, stream>>>(coords, box, pk2p, part, N, NL, kmax);

    int outb = (4*N + NT - 1)/NT + 1;
    k_fin<<<outb, NT, 0, stream>>>(part, q, p, box, eblk, r2b, selfp, S1,
                                   (float*)d_out, N, S2);
}

// Round 10
// 56.780 us; speedup vs baseline: 14.4737x; 1.2756x over previous
//
#include <hip/hip_runtime.h>

#define PI_F      3.14159265358979f
#define TWO_PI_F  6.28318530717959f
#define ALPHA_F   0.3f
#define NT        256
#define NT1       128   // pass-1 block size
#define L1        13    // kz slots per pass-1 thread (2 threads cover a 25-line)
#define LPAD      26    // padded line length in psr/psi
#define RSB       8     // reduce sub-sums per k (within one block)
#define AP2       8     // atoms per pass-2 block
#define TP2       32    // threads per atom in pass 2
#define ACHMAX    32    // max atoms per pass-1 slice (runtime 30)

// sin/cos of 2*pi*u using the hardware trig units (input in revolutions).
__device__ __forceinline__ void sincos2pi(float u, float& s, float& c) {
#if __has_builtin(__builtin_amdgcn_fractf)
    float uf = __builtin_amdgcn_fractf(u);
#else
    float uf = u - floorf(u);
#endif
    asm("v_sin_f32 %0, %1" : "=v"(s) : "v"(uf));
    asm("v_cos_f32 %0, %1" : "=v"(c) : "v"(uf));
}

// 3x3 inverse (row-major).
__device__ __forceinline__ void inv3(const float* b, float* inv) {
    float c00 = b[4]*b[8] - b[5]*b[7];
    float c01 = b[2]*b[7] - b[1]*b[8];
    float c02 = b[1]*b[5] - b[2]*b[4];
    float c10 = b[5]*b[6] - b[3]*b[8];
    float c11 = b[0]*b[8] - b[2]*b[6];
    float c12 = b[2]*b[3] - b[0]*b[5];
    float c20 = b[3]*b[7] - b[4]*b[6];
    float c21 = b[1]*b[6] - b[0]*b[7];
    float c22 = b[0]*b[4] - b[1]*b[3];
    float det = b[0]*c00 + b[1]*c10 + b[2]*c20;
    float id = 1.0f/det;
    inv[0]=c00*id; inv[1]=c01*id; inv[2]=c02*id;
    inv[3]=c10*id; inv[4]=c11*id; inv[5]=c12*id;
    inv[6]=c20*id; inv[7]=c21*id; inv[8]=c22*id;
}

// original k index -> (line, slot); kz = slot - kmax.
__device__ __forceinline__ void kmap(int k, int kmax, int LINELEN, int& line, int& slot) {
    if (k < kmax) { line = 0; slot = k + 1 + kmax; }
    else { int r = k - kmax; line = 1 + r / LINELEN; slot = r % LINELEN; }
}

// line index -> (kx,ky)
__device__ __forceinline__ void lmap(int line, int kmax, int LINELEN, int& kxi, int& kyi) {
    if (line == 0) { kxi=0; kyi=0; }
    else if (line <= kmax) { kxi=0; kyi=line; }
    else { int lp = line - kmax - 1; kxi = 1 + lp/LINELEN; kyi = lp - (kxi-1)*LINELEN - kmax; }
}

// ---------------- pass 1 (fused atom-prep + self-energy partials) ----------------
// grid (gx1, S1): y-block = one slice of ACH atoms (self-prepped into LDS);
// thread owns half a (kx,ky) line (L1 kz slots), phase recurrence along kz.
__global__ __launch_bounds__(NT1) void k_pass1(
        const float* __restrict__ coords, const float* __restrict__ box,
        const float* __restrict__ q, const float* __restrict__ p,
        const float* __restrict__ t,
        float* __restrict__ psr, float* __restrict__ psi, float* __restrict__ selfp,
        int N, int kmax, int NL, int K2, int ACH) {
    const int tid = threadIdx.x;
    const int LINELEN = 2*kmax + 1;
    float b[9], bi[9];
    #pragma unroll
    for (int j=0;j<9;++j) b[j]=box[j];
    inv3(b, bi);

    __shared__ float4 lat[(ACHMAX+1)*4];
    int slice = blockIdx.y;
    int n0 = slice*ACH;
    int mcnt = min(ACH, max(0, N - n0));
    float sq=0.f, sp=0.f, st=0.f;
    if (tid <= ACH) {
        int a = tid;
        float4 r0=make_float4(0.f,0.f,0.f,0.f), r1=r0, r2=r0, r3=r0;
        if (a < mcnt) {
            int n = n0 + a;
            const float c1 = TWO_PI_F*TWO_PI_F/3.0f;
            const float* tn = t + 9*(size_t)n;
            float rx=coords[3*n], ry=coords[3*n+1], rz=coords[3*n+2];
            float qq = q[n];
            float p0=p[3*n],p1=p[3*n+1],p2=p[3*n+2];
            float u1 = bi[0]*rx + bi[1]*ry + bi[2]*rz;
            float u2 = bi[3]*rx + bi[4]*ry + bi[5]*rz;
            float u3 = bi[6]*rx + bi[7]*ry + bi[8]*rz;
            float P1v = TWO_PI_F*(bi[0]*p0 + bi[1]*p1 + bi[2]*p2);
            float P2v = TWO_PI_F*(bi[3]*p0 + bi[4]*p1 + bi[5]*p2);
            float P3v = TWO_PI_F*(bi[6]*p0 + bi[7]*p1 + bi[8]*p2);
            float t0=tn[0],t1=tn[1],t2=tn[2],t3=tn[3],t4=tn[4],
                  t5=tn[5],t6=tn[6],t7=tn[7],t8=tn[8];
            float w1x = bi[0]*t0 + bi[1]*t3 + bi[2]*t6;
            float w1y = bi[0]*t1 + bi[1]*t4 + bi[2]*t7;
            float w1z = bi[0]*t2 + bi[1]*t5 + bi[2]*t8;
            float w2x = bi[3]*t0 + bi[4]*t3 + bi[5]*t6;
            float w2y = bi[3]*t1 + bi[4]*t4 + bi[5]*t7;
            float w2z = bi[3]*t2 + bi[4]*t5 + bi[5]*t8;
            float w3x = bi[6]*t0 + bi[7]*t3 + bi[8]*t6;
            float w3y = bi[6]*t1 + bi[7]*t4 + bi[8]*t7;
            float w3z = bi[6]*t2 + bi[7]*t5 + bi[8]*t8;
            float Q11 = w1x*bi[0] + w1y*bi[1] + w1z*bi[2];
            float Q12 = w1x*bi[3] + w1y*bi[4] + w1z*bi[5];
            float Q13 = w1x*bi[6] + w1y*bi[7] + w1z*bi[8];
            float Q21 = w2x*bi[0] + w2y*bi[1] + w2z*bi[2];
            float Q22 = w2x*bi[3] + w2y*bi[4] + w2z*bi[5];
            float Q23 = w2x*bi[6] + w2y*bi[7] + w2z*bi[8];
            float Q31 = w3x*bi[0] + w3y*bi[1] + w3z*bi[2];
            float Q32 = w3x*bi[3] + w3y*bi[4] + w3z*bi[5];
            float Q33 = w3x*bi[6] + w3y*bi[7] + w3z*bi[8];
            float c3v, s3v; sincos2pi(u3, s3v, c3v);
            r0 = make_float4(u1,u2,u3,qq);
            r1 = make_float4(c3v,s3v,P1v,P2v);
            r2 = make_float4(P3v,c1*Q11,c1*Q22,c1*Q33);
            r3 = make_float4(c1*(Q12+Q21),c1*(Q13+Q31),c1*(Q23+Q32),0.f);
            sq = qq*qq;
            sp = p0*p0 + p1*p1 + p2*p2;
            st = t0*t0+t1*t1+t2*t2+t3*t3+t4*t4+t5*t5+t6*t6+t7*t7+t8*t8;
        }
        lat[4*a+0]=r0; lat[4*a+1]=r1; lat[4*a+2]=r2; lat[4*a+3]=r3;
    }
    if (blockIdx.x == 0 && tid < 64) {
        for (int o=32;o;o>>=1){
            sq += __shfl_down(sq,o,64); sp += __shfl_down(sp,o,64); st += __shfl_down(st,o,64);
        }
        if (tid==0){
            selfp[4*slice+0]=sq; selfp[4*slice+1]=sp; selfp[4*slice+2]=st;
        }
    }
    __syncthreads();

    int seg = blockIdx.x*NT1 + tid;
    bool act = seg < NL*2;
    int line = act ? (seg>>1) : 0;
    int half = seg & 1;
    int kxi=0, kyi=0;
    if (act) lmap(line, kmax, LINELEN, kxi, kyi);
    float fkx = (float)kxi, fky = (float)kyi;
    float fkz0 = act ? (float)(half*L1 - kmax) : 0.f;
    float kx2 = fkx*fkx, kxky = fkx*fky, ky2 = fky*fky;
    float kz02 = fkz0*fkz0, tkz0 = 2.0f*fkz0;

    float sr[L1], si[L1];
    #pragma unroll
    for (int j=0;j<L1;++j){ sr[j]=0.f; si[j]=0.f; }

    float4 A0=lat[0],A1=lat[1],A2=lat[2],A3v=lat[3];
    #pragma unroll 2
    for (int j=0;j<mcnt;++j) {
        float4 B0=lat[4*(j+1)+0], B1=lat[4*(j+1)+1];
        float4 B2=lat[4*(j+1)+2], B3=lat[4*(j+1)+3];
        float u1=A0.x, u2=A0.y, u3=A0.z, qn=A0.w;
        float c3=A1.x, s3=A1.y, P1v=A1.z, P2v=A1.w;
        float P3v=A2.x, M11=A2.y, M22=A2.z, M33=A2.w;
        float M12=A3v.x, M13=A3v.y, M23=A3v.z;
        float ub = fkx*u1 + fky*u2 + fkz0*u3;
        float cc, ss; sincos2pi(ub, ss, cc);
        float Lib = fkx*P1v + fky*P2v + fkz0*P3v;
        float Aq = kx2*M11 + kxky*M12 + ky2*M22;
        float Bq = fkx*M13 + fky*M23;
        float Cq = M33;
        float A2q = Aq + fkz0*Bq + kz02*Cq;
        float B2q = fmaf(tkz0, Cq, Bq);
        #pragma unroll
        for (int jj=0;jj<L1;++jj) {
            float jf = (float)jj;
            float quad = fmaf(jf*jf, Cq, fmaf(jf, B2q, A2q));
            float Li = fmaf(jf, P3v, Lib);
            float Lr = qn - quad;
            sr[jj] = fmaf(cc, Lr, sr[jj]); sr[jj] = fmaf(-ss, Li, sr[jj]);
            si[jj] = fmaf(cc, Li, si[jj]); si[jj] = fmaf(ss, Lr, si[jj]);
            if (jj+1 < L1) {
                float tmp = ss*s3;
                float cn = fmaf(cc, c3, -tmp);
                float tmp2 = cc*s3;
                float sn = fmaf(ss, c3, tmp2);
                cc = cn; ss = sn;
            }
        }
        A0=B0;A1=B1;A2=B2;A3v=B3;
    }
    if (act) {
        size_t base = (size_t)slice*K2 + (size_t)line*LPAD + half*L1;
        #pragma unroll
        for (int j=0;j<L1;++j){ psr[base+j]=sr[j]; psi[base+j]=si[j]; }
    }
}

// ---------------- reduce (fused): block = 32 k's; thread (rs,klocal) sums S1/RSB
// slices; LDS combine; gaussian; write pk2p + per-block energy partials ----------------
__global__ __launch_bounds__(NT) void k_reduce(const float* __restrict__ psr,
        const float* __restrict__ psi, const float* __restrict__ kvecs,
        const float* __restrict__ box, float* __restrict__ pk2p,
        float* __restrict__ eblk, int K, int K2, int S1, int kmax, int NL) {
    const int tid = threadIdx.x;
    const int LINELEN = 2*kmax+1;
    int klocal = tid & 31, rs = tid >> 5;
    int k = blockIdx.x*32 + klocal;
    float srr=0.f, sii=0.f;
    if (k < K) {
        int line, slot; kmap(k, kmax, LINELEN, line, slot);
        size_t pk = (size_t)line*LPAD + slot;
        #pragma unroll 5
        for (int s=rs; s<S1; s+=RSB){
            srr += psr[(size_t)s*K2 + pk];
            sii += psi[(size_t)s*K2 + pk];
        }
    }
    __shared__ float lr[NT], li[NT];
    lr[tid]=srr; li[tid]=sii;
    __syncthreads();
    if (tid < 32) {
        float sr=0.f, si=0.f;
        #pragma unroll
        for (int r=0;r<RSB;++r){ sr+=lr[r*32+tid]; si+=li[r*32+tid]; }
        float ek = 0.f;
        if (k < K) {
            float b[9], bi[9];
            #pragma unroll
            for (int j=0;j<9;++j) b[j]=box[j];
            inv3(b, bi);
            float kx=kvecs[3*k], ky=kvecs[3*k+1], kz=kvecs[3*k+2];
            float ax = kx*bi[0] + ky*bi[3] + kz*bi[6];
            float ay = kx*bi[1] + ky*bi[4] + kz*bi[7];
            float az = kx*bi[2] + ky*bi[5] + kz*bi[8];
            float ksq = ax*ax + ay*ay + az*az;
            float g = expf(-PI_F*PI_F*ksq/(ALPHA_F*ALPHA_F)) / ksq;
            float srg = g*sr, sig = g*si;
            int line, slot; kmap(k, kmax, LINELEN, line, slot);
            pk2p[2*((size_t)line*LINELEN + slot)+0] = srg;
            pk2p[2*((size_t)line*LINELEN + slot)+1] = sig;
            ek = srg*sr + sig*si;
        }
        for (int o=16;o;o>>=1) ek += __shfl_down(ek,o,32);
        if (tid==0) eblk[blockIdx.x] = ek;
    }
    // zero the never-written pads: line 0, slots 0..kmax
    if (blockIdx.x == 0 && tid >= 64 && tid < 64 + 2*(kmax+1))
        pk2p[tid - 64] = 0.f;
}

// ---------------- pass 2 (block-reduced, writes final outputs; block 0 adds energy) ----
// block = AP2 atoms x TP2 threads. tid = tsub*AP2 + alocal. Thread walks lines
// l = tsub, tsub+TP2, ... with the kz phase recurrence; in-block reduce.
__global__ __launch_bounds__(NT) void k_pass2(const float* __restrict__ coords,
        const float* __restrict__ q, const float* __restrict__ p,
        const float* __restrict__ box, const float* __restrict__ pk2p,
        const float* __restrict__ eblk, int nblk,
        const float* __restrict__ selfp, int nself,
        float* __restrict__ out, int N, int NL, int kmax) {
    const int tid = threadIdx.x;
    const int LINELEN = 2*kmax+1;
    float b[9], bi[9];
    #pragma unroll
    for (int j=0;j<9;++j) b[j]=box[j];
    inv3(b, bi);
    float V = b[0]*(b[4]*b[8]-b[5]*b[7]) + b[1]*(b[5]*b[6]-b[3]*b[8])
            + b[2]*(b[3]*b[7]-b[4]*b[6]);
    float arpi = ALPHA_F/sqrtf(PI_F);
    float a2 = ALPHA_F*ALPHA_F;

    int alocal = tid & (AP2-1);
    int tsub   = tid >> 3;           // 0..TP2-1
    int n = blockIdx.x*AP2 + alocal;
    bool act = n < N;
    float rx=0.f, ry=0.f, rz=0.f;
    if (act){ rx=coords[3*n]; ry=coords[3*n+1]; rz=coords[3*n+2]; }
    float u1 = bi[0]*rx + bi[1]*ry + bi[2]*rz;
    float u2 = bi[3]*rx + bi[4]*ry + bi[5]*rz;
    float u3 = bi[6]*rx + bi[7]*ry + bi[8]*rz;
    float c3, s3; sincos2pi(u3, s3, c3);
    float pot=0.f, F1=0.f, F2=0.f, F3=0.f;
    float fkzb = -(float)kmax;

    for (int l = tsub; l < NL; l += TP2) {
        int kxi, kyi; lmap(l, kmax, LINELEN, kxi, kyi);
        float fkx = (float)kxi, fky = (float)kyi;
        float ub = fkx*u1 + fky*u2 + fkzb*u3;
        float cc, ss; sincos2pi(ub, ss, cc);
        const float2* pl = (const float2*)(pk2p + 2*(size_t)l*LINELEN);
        #pragma unroll 5
        for (int j=0;j<LINELEN;++j) {
            float2 sg = pl[j];
            float fkz = (float)(j - kmax);
            pot = fmaf(sg.x, cc, pot);
            pot = fmaf(sg.y, ss, pot);
            float kim = sg.x*ss;
            kim = fmaf(-sg.y, cc, kim);
            F1 = fmaf(fkx, kim, F1);
            F2 = fmaf(fky, kim, F2);
            F3 = fmaf(fkz, kim, F3);
            float tmp = ss*s3;
            float cn = fmaf(cc, c3, -tmp);
            float tmp2 = cc*s3;
            ss = fmaf(ss, c3, tmp2);
            cc = cn;
        }
    }
    // reduce across the 8 tsub-groups within each wave (lane = tsubw*8 + alocal)
    #pragma unroll
    for (int o=32;o>=8;o>>=1) {
        pot += __shfl_down(pot,o,64);
        F1  += __shfl_down(F1,o,64);
        F2  += __shfl_down(F2,o,64);
        F3  += __shfl_down(F3,o,64);
    }
    __shared__ float red[4][4][AP2];   // [wave][comp][atom]
    int w = tid >> 6, lane = tid & 63;
    if (lane < AP2) {
        red[w][0][lane]=pot; red[w][1][lane]=F1; red[w][2][lane]=F2; red[w][3][lane]=F3;
    }
    __syncthreads();
    if (tid < AP2 && act) {
        float P  = red[0][0][tid]+red[1][0][tid]+red[2][0][tid]+red[3][0][tid];
        float f1 = red[0][1][tid]+red[1][1][tid]+red[2][1][tid]+red[3][1][tid];
        float f2 = red[0][2][tid]+red[1][2][tid]+red[2][2][tid]+red[3][2][tid];
        float f3 = red[0][3][tid]+red[1][3][tid]+red[2][3][tid]+red[3][3][tid];
        int nn = blockIdx.x*AP2 + tid;
        float fx = f1*bi[0] + f2*bi[3] + f3*bi[6];
        float fy = f1*bi[1] + f2*bi[4] + f3*bi[7];
        float fz = f1*bi[2] + f2*bi[5] + f3*bi[8];
        out[1+nn] = (2.0f/(PI_F*V))*P - 2.0f*arpi*q[nn];
        float cp2 = arpi*(4.0f*a2/3.0f);
        out[1+N+3*nn+0] = (4.0f/V)*fx + cp2*p[3*nn+0];
        out[1+N+3*nn+1] = (4.0f/V)*fy + cp2*p[3*nn+1];
        out[1+N+3*nn+2] = (4.0f/V)*fz + cp2*p[3*nn+2];
    }
    // energy finalization on block 0, wave 0
    if (blockIdx.x == 0 && tid < 64) {
        float e=0.f, sq=0.f, sp=0.f, st=0.f;
        for (int i=tid;i<nblk;i+=64) e += eblk[i];
        for (int i=tid;i<nself;i+=64){ sq+=selfp[4*i]; sp+=selfp[4*i+1]; st+=selfp[4*i+2]; }
        for (int o=32;o;o>>=1) {
            e += __shfl_down(e,o,64); sq += __shfl_down(sq,o,64);
            sp += __shfl_down(sp,o,64); st += __shfl_down(st,o,64);
        }
        if (tid==0) {
            out[0] = e/(PI_F*V) - arpi*sq - arpi*(2.0f*a2/3.0f)*sp
                   - arpi*(8.0f*a2*a2/45.0f)*st;
        }
    }
}

extern "C" void kernel_launch(void* const* d_in, const int* in_sizes, int n_in,
                              void* d_out, int out_size, void* d_ws, size_t ws_size,
                              hipStream_t stream) {
    const float* coords = (const float*)d_in[0];
    const float* box    = (const float*)d_in[1];
    const float* q      = (const float*)d_in[2];
    const float* p      = (const float*)d_in[3];
    const float* t      = (const float*)d_in[4];
    const float* kvecs  = (const float*)d_in[5];
    int N = in_sizes[0]/3;
    int K = in_sizes[5]/3;

    int kmax = 12;
    for (int km=1; km<=40; ++km) {
        long ll = 2l*km+1;
        if ((long)km*(ll*ll + ll + 1) == (long)K) { kmax = km; break; }
    }
    int LINELEN = 2*kmax+1;                 // 25
    int NL = 1 + kmax + kmax*LINELEN;       // 313
    int K2 = NL*LPAD;                       // 8138
    int S1 = (N + 29)/30;                   // 200 slices
    int ACH = (N + S1 - 1)/S1;              // 30 atoms/slice (<= ACHMAX)
    int gx1 = (2*NL + NT1 - 1)/NT1;         // 5

    float* ws = (float*)d_ws;
    size_t off = 0;
    float* psr   = ws + off; off += (size_t)S1*K2;
    float* psi   = ws + off; off += (size_t)S1*K2;
    float* pk2p  = ws + off; off += 2*(size_t)NL*LINELEN;
    float* selfp = ws + off; off += 4*(size_t)S1;
    float* eblk  = ws + off; off += 512;

    dim3 g1(gx1, S1);
    k_pass1<<<g1, NT1, 0, stream>>>(coords, box, q, p, t, psr, psi, selfp,
                                    N, kmax, NL, K2, ACH);

    int kb2 = (K + 31)/32;                  // 245
    k_reduce<<<kb2, NT, 0, stream>>>(psr, psi, kvecs, box, pk2p, eblk,
                                     K, K2, S1, kmax, NL);

    int nb3 = (N + AP2 - 1)/AP2;            // 750
    k_pass2<<<nb3, NT, 0, stream>>>(coords, q, p, box, pk2p, eblk, kb2,
                                    selfp, S1, (float*)d_out, N, NL, kmax);
}